// Round 17
// baseline (675.696 us; speedup 1.0000x reference)
//
#include <hip/hip_runtime.h>

constexpr int NUM_USERS = 100000;
constexpr int NUM_ITEMS = 50000;
constexpr int DIM = 64;
constexpr int NNZ_R = 3200000;
constexpr int NNZ_S = 2000000;
constexpr int NNZ_TOT = NNZ_R + NNZ_R + NNZ_S;   // 8.4M entries, one array

constexpr int BSH_U = 8, BROWS_U = 256;     // user/social buckets: 256 rows
constexpr int BSH_I = 7, BROWS_I = 128;     // item buckets: 128 rows
constexpr int NC_U = (NUM_USERS + BROWS_U - 1) / BROWS_U;   // 391
constexpr int NC_I = (NUM_ITEMS + BROWS_I - 1) / BROWS_I;   // 391
constexpr int NC_S = NC_U;                                  // 391
constexpr int NC = NC_U + NC_I + NC_S;                      // 1173
constexpr int NBLK = 256;                   // build blocks, 1/CU
constexpr int NPB = NBLK * NC;
constexpr int CHUNK_R = NNZ_R / NBLK;       // 12500 exact
constexpr int CHUNK_S = (NNZ_S + NBLK - 1) / NBLK;  // 7813

constexpr int SB_EDGES = 4096;              // R sub-batch: 4096 edges -> 8192 entries
constexpr int SB_PAIRS = 8192;
constexpr int NKEY = 2048;                  // 256 lrow x 8 col-quadrants

__device__ __forceinline__ float bf2f(unsigned short u) {
    return __uint_as_float((unsigned)u << 16);
}
__device__ __forceinline__ unsigned short f2bf(float f) {   // round-to-nearest-even
    unsigned u = __float_as_uint(f);
    return (unsigned short)((u + 0x7FFFu + ((u >> 16) & 1u)) >> 16);
}
__device__ __forceinline__ float bflo(unsigned r) { return __uint_as_float(r << 16); }
__device__ __forceinline__ float bfhi(unsigned r) { return __uint_as_float(r & 0xFFFF0000u); }

// ---- pass A: LDS histogram; per-(block,bucket) counts BUCKET-MAJOR ----
__global__ __launch_bounds__(1024) void hist_lds(const int* __restrict__ rr,
                                                 const int* __restrict__ rc,
                                                 const int* __restrict__ sr,
                                                 int* __restrict__ cntPB /* [NC][NBLK] */) {
    __shared__ int lds[NC];
    int k = blockIdx.x, tid = threadIdx.x;
    for (int c = tid; c < NC; c += 1024) lds[c] = 0;
    __syncthreads();
    int r0 = k * CHUNK_R, r1 = r0 + CHUNK_R;
    int s0 = k * CHUNK_S, s1 = min(s0 + CHUNK_S, NNZ_S);
    for (int i = r0 + tid; i < r1; i += 1024) {
        atomicAdd(&lds[rr[i] >> BSH_U], 1);
        atomicAdd(&lds[NC_U + (rc[i] >> BSH_I)], 1);
    }
    for (int i = s0 + tid; i < s1; i += 1024)
        atomicAdd(&lds[NC_U + NC_I + (sr[i] >> BSH_U)], 1);
    __syncthreads();
    for (int c = tid; c < NC; c += 1024) cntPB[c * NBLK + k] = lds[c];
}

// ---- per-bucket exscan over NBLK block-counts (one block per bucket) ----
__global__ __launch_bounds__(NBLK) void scan_bkt(int* __restrict__ cntPB,
                                                 int* __restrict__ bktTot) {
    int c = blockIdx.x, t = threadIdx.x;
    __shared__ int sh[NBLK];
    int v = cntPB[c * NBLK + t];
    sh[t] = v;
    __syncthreads();
    for (int off = 1; off < NBLK; off <<= 1) {
        int u = (t >= off) ? sh[t - off] : 0;
        __syncthreads();
        sh[t] += u;
        __syncthreads();
    }
    cntPB[c * NBLK + t] = sh[t] - v;
    if (t == NBLK - 1) bktTot[c] = sh[t];
}

// ---- tiny top-level exscan over NC bucket totals ----
__global__ __launch_bounds__(1024) void scan_top(int* __restrict__ B /* NC+1 */) {
    __shared__ int part[1024];
    int t = threadIdx.x;
    const int chunk = (NC + 1023) >> 10;
    int lo = t * chunk, hi = min(lo + chunk, NC);
    int s = 0;
    for (int i = lo; i < hi; ++i) s += B[i];
    part[t] = s;
    __syncthreads();
    for (int off = 1; off < 1024; off <<= 1) {
        int v = (t >= off) ? part[t - off] : 0;
        __syncthreads();
        part[t] += v;
        __syncthreads();
    }
    int excl = (t == 0) ? 0 : part[t - 1];
    for (int i = lo; i < hi; ++i) {
        int v = B[i];
        B[i] = excl;
        excl += v;
    }
    if (t == 1023) B[NC] = part[1023];
}

// ---- pass B: LDS-staged sub-batch sort, then wave-coalesced contiguous writes ----
__global__ __launch_bounds__(1024) void bin_pass(const int* __restrict__ rr,
                                                 const int* __restrict__ rc,
                                                 const float* __restrict__ rv,
                                                 const int* __restrict__ sr,
                                                 const int* __restrict__ sc,
                                                 const float* __restrict__ sv,
                                                 const int* __restrict__ cntPB,
                                                 const int* __restrict__ bktBase,
                                                 int2* __restrict__ ent) {
    __shared__ int cur[NC];
    __shared__ int cnt[NC];
    __shared__ int lstart[NC];
    __shared__ int lcur[NC];
    __shared__ int part[1024];
    __shared__ int2 stage[SB_PAIRS];
    __shared__ int gaddr[SB_PAIRS];
    int k = blockIdx.x, tid = threadIdx.x;
    for (int c = tid; c < NC; c += 1024)
        cur[c] = bktBase[c] + cntPB[c * NBLK + k];

    int r0 = k * CHUNK_R;
    for (int sb = 0; sb < CHUNK_R; sb += SB_EDGES) {
        int nE = min(SB_EDGES, CHUNK_R - sb);
        int base = r0 + sb;
        for (int c = tid; c < NC; c += 1024) { cnt[c] = 0; lcur[c] = 0; }
        __syncthreads();
        for (int i = tid; i < nE; i += 1024) {
            atomicAdd(&cnt[rr[base + i] >> BSH_U], 1);
            atomicAdd(&cnt[NC_U + (rc[base + i] >> BSH_I)], 1);
        }
        __syncthreads();
        int o0 = 2 * tid, o1 = 2 * tid + 1;
        int a = (o0 < NC) ? cnt[o0] : 0;
        int b = (o1 < NC) ? cnt[o1] : 0;
        part[tid] = a + b;
        __syncthreads();
        for (int off = 1; off < 1024; off <<= 1) {
            int v = (tid >= off) ? part[tid - off] : 0;
            __syncthreads();
            part[tid] += v;
            __syncthreads();
        }
        int ex = (tid == 0) ? 0 : part[tid - 1];
        if (o0 < NC) lstart[o0] = ex;
        if (o1 < NC) lstart[o1] = ex + a;
        __syncthreads();
        for (int i = tid; i < nE; i += 1024) {
            int r = rr[base + i], c = rc[base + i];
            int v = __float_as_int(rv[base + i]);
            int cu_ = r >> BSH_U;
            int j = atomicAdd(&lcur[cu_], 1);
            int lp = lstart[cu_] + j;
            stage[lp] = make_int2(((r & (BROWS_U - 1)) << 17) | c, v);
            gaddr[lp] = cur[cu_] + j;
            int ci_ = NC_U + (c >> BSH_I);
            int j2 = atomicAdd(&lcur[ci_], 1);
            int lp2 = lstart[ci_] + j2;
            stage[lp2] = make_int2(((c & (BROWS_I - 1)) << 17) | r, v);
            gaddr[lp2] = cur[ci_] + j2;
        }
        __syncthreads();
        int nP = 2 * nE;
        for (int s = tid; s < nP; s += 1024)
            ent[gaddr[s]] = stage[s];
        for (int c = tid; c < NC; c += 1024) cur[c] += cnt[c];
        __syncthreads();
    }

    int s0 = k * CHUNK_S, sEnd = min(s0 + CHUNK_S, NNZ_S);
    for (int sb = s0; sb < sEnd; sb += SB_PAIRS) {
        int nE = min(SB_PAIRS, sEnd - sb);
        for (int c = tid; c < NC; c += 1024) { cnt[c] = 0; lcur[c] = 0; }
        __syncthreads();
        for (int i = tid; i < nE; i += 1024)
            atomicAdd(&cnt[NC_U + NC_I + (sr[sb + i] >> BSH_U)], 1);
        __syncthreads();
        int o0 = 2 * tid, o1 = 2 * tid + 1;
        int a = (o0 < NC) ? cnt[o0] : 0;
        int b = (o1 < NC) ? cnt[o1] : 0;
        part[tid] = a + b;
        __syncthreads();
        for (int off = 1; off < 1024; off <<= 1) {
            int v = (tid >= off) ? part[tid - off] : 0;
            __syncthreads();
            part[tid] += v;
            __syncthreads();
        }
        int ex = (tid == 0) ? 0 : part[tid - 1];
        if (o0 < NC) lstart[o0] = ex;
        if (o1 < NC) lstart[o1] = ex + a;
        __syncthreads();
        for (int i = tid; i < nE; i += 1024) {
            int r = sr[sb + i];
            int cs_ = NC_U + NC_I + (r >> BSH_U);
            int j = atomicAdd(&lcur[cs_], 1);
            int lp = lstart[cs_] + j;
            stage[lp] = make_int2(((r & (BROWS_U - 1)) << 17) | sc[sb + i],
                                  __float_as_int(sv[sb + i]));
            gaddr[lp] = cur[cs_] + j;
        }
        __syncthreads();
        for (int s = tid; s < nE; s += 1024)
            ent[gaddr[s]] = stage[s];
        for (int c = tid; c < NC; c += 1024) cur[c] += cnt[c];
        __syncthreads();
    }
}

// ---- per-bucket counting sort, key = (lrow<<3)|colQuad: entries within each row
//      come out in ascending column-octant order -> concurrent waves sweep the
//      operand table in a moving ~1/8 window that fits per-XCD L2. ----
__global__ __launch_bounds__(512) void sort_buckets(const int2* __restrict__ src,
                                                    int2* __restrict__ dst,
                                                    const int* __restrict__ bktBase,
                                                    int* __restrict__ rPu,
                                                    int* __restrict__ rPi,
                                                    int* __restrict__ rPs) {
    int gb = blockIdx.x;
    int* rowptr;
    int brows, lb, nrows, csh;
    if (gb < NC_U)              { rowptr = rPu; brows = BROWS_U; lb = gb;               nrows = NUM_USERS; csh = 13; }  // cols: items <50000 -> quad 0..6
    else if (gb < NC_U + NC_I)  { rowptr = rPi; brows = BROWS_I; lb = gb - NC_U;        nrows = NUM_ITEMS; csh = 14; }  // cols: users <100000 -> quad 0..6
    else                        { rowptr = rPs; brows = BROWS_U; lb = gb - NC_U - NC_I; nrows = NUM_USERS; csh = 14; }
    int t = threadIdx.x;
    __shared__ int cnt[NKEY];
    __shared__ int ofs[NKEY];
    __shared__ int part[512];
    for (int i = t; i < NKEY; i += 512) cnt[i] = 0;
    __syncthreads();
    int b0 = bktBase[gb], b1 = bktBase[gb + 1];
    for (int i = b0 + t; i < b1; i += 512) {
        int vx = src[i].x;
        int key = (((unsigned)vx >> 17) << 3) | ((vx & 0x1FFFF) >> csh);
        atomicAdd(&cnt[key], 1);
    }
    __syncthreads();
    // block exscan over NKEY (4 keys per thread)
    int k0 = 4 * t;
    int c0 = cnt[k0], c1 = cnt[k0 + 1], c2 = cnt[k0 + 2], c3 = cnt[k0 + 3];
    part[t] = c0 + c1 + c2 + c3;
    __syncthreads();
    for (int off = 1; off < 512; off <<= 1) {
        int v = (t >= off) ? part[t - off] : 0;
        __syncthreads();
        part[t] += v;
        __syncthreads();
    }
    int ex = (t == 0) ? 0 : part[t - 1];
    ofs[k0] = ex;
    ofs[k0 + 1] = ex + c0;
    ofs[k0 + 2] = ex + c0 + c1;
    ofs[k0 + 3] = ex + c0 + c1 + c2;
    __syncthreads();
    int gr = lb * brows + t;
    if (t < brows && gr < nrows) rowptr[gr] = b0 + ofs[t << 3];   // row start = quad-0 start
    if (gb == 0 && t == 0) {
        rPu[NUM_USERS] = NNZ_R;
        rPi[NUM_ITEMS] = 2 * NNZ_R;
        rPs[NUM_USERS] = NNZ_TOT;
    }
    __syncthreads();   // rowptr published before pass 2 mutates ofs
    for (int i = b0 + t; i < b1; i += 512) {
        int2 v = src[i];
        int key = (((unsigned)v.x >> 17) << 3) | ((v.x & 0x1FFFF) >> csh);
        int pos = b0 + atomicAdd(&ofs[key], 1);
        dst[pos] = make_int2(v.x & 0x1FFFF, v.y);
    }
}

// ---- CSR SpMM with acc-traffic elimination:
//      initsrc != null : acc = w0*bf16(initsrc) + w*sum   (no acc read)
//      initsrc == null, acc != null : acc += w*sum        (RMW)
//      acc == null : bf16 out only                        (deferred to finalize) ----
struct SpmmOp {
    const int* rowptr;
    const int2* ent;
    const unsigned short* x;        // bf16 rows [*][64]
    unsigned short* out;            // bf16, nullable
    float* acc;                     // f32 (d_out), nullable
    const unsigned short* initsrc;  // bf16 init term, nullable
    float w;
    float w0;
    int nrows;
};

__global__ __launch_bounds__(256, 4) void spmm2(SpmmOp A, SpmmOp B, int ablocks) {
    bool isA = (int)blockIdx.x < ablocks;
    SpmmOp op = isA ? A : B;
    int bid = isA ? blockIdx.x : blockIdx.x - ablocks;
    int row = bid * 4 + (threadIdx.x >> 6);
    if (row >= op.nrows) return;
    int lane = threadIdx.x & 63;
    int g = lane >> 4;          // edge group 0..3
    int q = lane & 15;          // quarter-row slot: dims 4q..4q+3
    const int2* __restrict__ ent = op.ent;
    const unsigned short* __restrict__ x = op.x;
    int e = op.rowptr[row], end = op.rowptr[row + 1];
    float s0 = 0.f, s1 = 0.f, s2 = 0.f, s3 = 0.f;
    for (; e + 16 <= end; e += 16) {            // 4 edges per group, 16 per wave-iter
        int2 n0 = ent[e + g];
        int2 n1 = ent[e + 4 + g];
        int2 n2 = ent[e + 8 + g];
        int2 n3 = ent[e + 12 + g];
        uint2 r0 = *reinterpret_cast<const uint2*>(x + (size_t)n0.x * DIM + q * 4);
        uint2 r1 = *reinterpret_cast<const uint2*>(x + (size_t)n1.x * DIM + q * 4);
        uint2 r2 = *reinterpret_cast<const uint2*>(x + (size_t)n2.x * DIM + q * 4);
        uint2 r3 = *reinterpret_cast<const uint2*>(x + (size_t)n3.x * DIM + q * 4);
        float v0 = __int_as_float(n0.y), v1 = __int_as_float(n1.y);
        float v2 = __int_as_float(n2.y), v3 = __int_as_float(n3.y);
        s0 += v0 * bflo(r0.x); s1 += v0 * bfhi(r0.x); s2 += v0 * bflo(r0.y); s3 += v0 * bfhi(r0.y);
        s0 += v1 * bflo(r1.x); s1 += v1 * bfhi(r1.x); s2 += v1 * bflo(r1.y); s3 += v1 * bfhi(r1.y);
        s0 += v2 * bflo(r2.x); s1 += v2 * bfhi(r2.x); s2 += v2 * bflo(r2.y); s3 += v2 * bfhi(r2.y);
        s0 += v3 * bflo(r3.x); s1 += v3 * bfhi(r3.x); s2 += v3 * bflo(r3.y); s3 += v3 * bfhi(r3.y);
    }
    if (e < end) {                              // single predicated 16-wide tail step
        int t0 = e + 4 * g;
        int lim = end - 1;
        int c0 = min(t0, lim),     c1 = min(t0 + 1, lim);
        int c2 = min(t0 + 2, lim), c3 = min(t0 + 3, lim);
        int2 n0 = ent[c0];
        int2 n1 = ent[c1];
        int2 n2 = ent[c2];
        int2 n3 = ent[c3];
        uint2 r0 = *reinterpret_cast<const uint2*>(x + (size_t)n0.x * DIM + q * 4);
        uint2 r1 = *reinterpret_cast<const uint2*>(x + (size_t)n1.x * DIM + q * 4);
        uint2 r2 = *reinterpret_cast<const uint2*>(x + (size_t)n2.x * DIM + q * 4);
        uint2 r3 = *reinterpret_cast<const uint2*>(x + (size_t)n3.x * DIM + q * 4);
        float v0 = (t0     < end) ? __int_as_float(n0.y) : 0.f;
        float v1 = (t0 + 1 < end) ? __int_as_float(n1.y) : 0.f;
        float v2 = (t0 + 2 < end) ? __int_as_float(n2.y) : 0.f;
        float v3 = (t0 + 3 < end) ? __int_as_float(n3.y) : 0.f;
        s0 += v0 * bflo(r0.x); s1 += v0 * bfhi(r0.x); s2 += v0 * bflo(r0.y); s3 += v0 * bfhi(r0.y);
        s0 += v1 * bflo(r1.x); s1 += v1 * bfhi(r1.x); s2 += v1 * bflo(r1.y); s3 += v1 * bfhi(r1.y);
        s0 += v2 * bflo(r2.x); s1 += v2 * bfhi(r2.x); s2 += v2 * bflo(r2.y); s3 += v2 * bfhi(r2.y);
        s0 += v3 * bflo(r3.x); s1 += v3 * bfhi(r3.x); s2 += v3 * bflo(r3.y); s3 += v3 * bfhi(r3.y);
    }
    s0 += __shfl_xor(s0, 16, 64); s0 += __shfl_xor(s0, 32, 64);
    s1 += __shfl_xor(s1, 16, 64); s1 += __shfl_xor(s1, 32, 64);
    s2 += __shfl_xor(s2, 16, 64); s2 += __shfl_xor(s2, 32, 64);
    s3 += __shfl_xor(s3, 16, 64); s3 += __shfl_xor(s3, 32, 64);
    if (g == 0) {                               // 16 lanes write the full row
        size_t base = (size_t)row * DIM + q * 4;
        if (op.out) {
            uint2 o;
            o.x = (unsigned)f2bf(s0) | ((unsigned)f2bf(s1) << 16);
            o.y = (unsigned)f2bf(s2) | ((unsigned)f2bf(s3) << 16);
            *reinterpret_cast<uint2*>(op.out + base) = o;
        }
        if (op.acc) {
            float4* a = reinterpret_cast<float4*>(op.acc + base);
            float4 av;
            if (op.initsrc) {
                uint2 iv = *reinterpret_cast<const uint2*>(op.initsrc + base);
                av.x = op.w0 * bflo(iv.x); av.y = op.w0 * bfhi(iv.x);
                av.z = op.w0 * bflo(iv.y); av.w = op.w0 * bfhi(iv.y);
            } else {
                av = *a;
            }
            av.x += op.w * s0; av.y += op.w * s1; av.z += op.w * s2; av.w += op.w * s3;
            *a = av;
        }
    }
}

// bf16 copies of the input embeddings (runs after build; aliases ent_bin region)
__global__ void to_bf16(const float* __restrict__ ue, const float* __restrict__ ie,
                        unsigned short* __restrict__ ueB, unsigned short* __restrict__ ieB,
                        int u4, int i4) {
    int i = blockIdx.x * blockDim.x + threadIdx.x;
    int st = gridDim.x * blockDim.x;
    int n4 = u4 + i4;
    for (; i < n4; i += st) {
        if (i < u4) {
            float4 v = reinterpret_cast<const float4*>(ue)[i];
            ushort4 b;
            b.x = f2bf(v.x); b.y = f2bf(v.y); b.z = f2bf(v.z); b.w = f2bf(v.w);
            reinterpret_cast<ushort4*>(ueB)[i] = b;
        } else {
            int j = i - u4;
            float4 v = reinterpret_cast<const float4*>(ie)[j];
            ushort4 b;
            b.x = f2bf(v.x); b.y = f2bf(v.y); b.z = f2bf(v.z); b.w = f2bf(v.w);
            reinterpret_cast<ushort4*>(ieB)[j] = b;
        }
    }
}

// finalize: fold deferred last-layer terms, then L2-normalize per row
__global__ void finalize_kernel(float* __restrict__ out,
                                const unsigned short* __restrict__ uC,  // u3
                                const unsigned short* __restrict__ s2,  // social layer 2
                                const unsigned short* __restrict__ iC) { // i3
    const float WU = 0.6f / 4.0f, WS = 0.4f / 3.0f, WI = 0.25f;
    int row = blockIdx.x * 4 + (threadIdx.x >> 6);
    if (row >= NUM_USERS + NUM_ITEMS) return;
    int d = threadIdx.x & 63;
    size_t idx = (size_t)row * DIM + d;
    float val = out[idx];
    if (row < NUM_USERS) {
        val += WU * bf2f(uC[idx]) + WS * bf2f(s2[idx]);
    } else {
        size_t iidx = idx - (size_t)NUM_USERS * DIM;
        val += WI * bf2f(iC[iidx]);
    }
    float sq = val * val;
    #pragma unroll
    for (int off = 32; off; off >>= 1) sq += __shfl_xor(sq, off, 64);
    out[idx] = val / fmaxf(sqrtf(sq), 1e-12f);
}

extern "C" void kernel_launch(void* const* d_in, const int* in_sizes, int n_in,
                              void* d_out, int out_size, void* d_ws, size_t ws_size,
                              hipStream_t stream) {
    const float* user_emb = (const float*)d_in[0];
    const float* item_emb = (const float*)d_in[1];
    const float* r_vals   = (const float*)d_in[2];
    const float* s_vals   = (const float*)d_in[3];
    const int*   r_rows   = (const int*)d_in[4];
    const int*   r_cols   = (const int*)d_in[5];
    const int*   s_rows   = (const int*)d_in[6];
    const int*   s_cols   = (const int*)d_in[7];

    const size_t U = (size_t)NUM_USERS * DIM;
    const size_t I = (size_t)NUM_ITEMS * DIM;

    // ---- workspace (~140 MB) ----
    int2* ent_sorted = (int2*)d_ws;                       // NNZ_TOT (67.2 MB), persistent
    char* region2 = (char*)(ent_sorted + NNZ_TOT);        // 70.4 MB union:
    int2* ent_bin = (int2*)region2;                       //   build-time entries (67.2)
    unsigned short* ueB = (unsigned short*)region2;       //   bf16: [ueB U][ieB I][uA U]
    unsigned short* ieB = ueB + U;                        //         [uB U][iA I][iB I][uC U]
    unsigned short* uA  = ieB + I;                        //   = (4U+3I)*2 = 70.4 MB
    unsigned short* uB  = uA + U;
    unsigned short* iA  = uB + U;
    unsigned short* iB  = iA + I;
    unsigned short* uC  = iB + I;
    unsigned short* s1b = uA;    // social 1 out: uA dead after D2
    unsigned short* s2b = ueB;   // social 2 out: ueB dead after so1
    unsigned short* iCb = ieB;   // i3 out: ieB dead after D1
    int* cntPB   = (int*)(uC + U);                        // [NC][NBLK] (1.2 MB)
    int* bktBase = cntPB + NPB;                           // NC+1
    int* rPu = bktBase + NC + 1;                          // NUM_USERS+1
    int* rPi = rPu + NUM_USERS + 1;                       // NUM_ITEMS+1
    int* rPs = rPi + NUM_ITEMS + 1;                       // NUM_USERS+1

    float* accU = (float*)d_out;
    float* accI = (float*)d_out + U;

    dim3 blk(256);

    // ---- build: hist -> per-bucket scan -> top scan -> staged scatter -> sort ----
    hist_lds<<<NBLK, 1024, 0, stream>>>(r_rows, r_cols, s_rows, cntPB);
    scan_bkt<<<NC, NBLK, 0, stream>>>(cntPB, bktBase);
    scan_top<<<1, 1024, 0, stream>>>(bktBase);
    bin_pass<<<NBLK, 1024, 0, stream>>>(r_rows, r_cols, r_vals, s_rows, s_cols, s_vals,
                                        cntPB, bktBase, ent_bin);
    sort_buckets<<<NC, 512, 0, stream>>>(ent_bin, ent_sorted, bktBase, rPu, rPi, rPs);

    to_bf16<<<2048, blk, 0, stream>>>(user_emb, item_emb, ueB, ieB,
                                      (int)(U / 4), (int)(I / 4));

    const float WU = 0.6f / 4.0f, WI = 0.25f, WS = 0.4f / 3.0f;
    const float WU0 = WU + WS;   // e_u weight: 0.15 + 0.4/3
    int ub = (NUM_USERS + 3) / 4, ib = (NUM_ITEMS + 3) / 4;

    // D1: acc-init (no acc read): accU = WU0*e_u + WU*u1 ; accI = WI*e_i + WI*i1
    SpmmOp u1{rPu, ent_sorted, ieB, uA, accU, ueB, WU, WU0, NUM_USERS};
    SpmmOp i1{rPi, ent_sorted, ueB, iA, accI, ieB, WI, WI, NUM_ITEMS};
    spmm2<<<ub + ib, blk, 0, stream>>>(u1, i1, ub);

    // D2: RMW
    SpmmOp u2{rPu, ent_sorted, iA, uB, accU, nullptr, WU, 0.f, NUM_USERS};
    SpmmOp i2{rPi, ent_sorted, uA, iB, accI, nullptr, WI, 0.f, NUM_ITEMS};
    spmm2<<<ub + ib, blk, 0, stream>>>(u2, i2, ub);

    // so1: RMW accU += WS*s1, out s1 (into uA, dead after D2)
    SpmmOp so1{rPs, ent_sorted, ueB, s1b, accU, nullptr, WS, 0.f, NUM_USERS};
    spmm2<<<ub, blk, 0, stream>>>(so1, so1, ub);

    // so2: out-only s2 (into ueB, dead after so1); folded in finalize
    SpmmOp so2{rPs, ent_sorted, s1b, s2b, nullptr, nullptr, 0.f, 0.f, NUM_USERS};
    spmm2<<<ub, blk, 0, stream>>>(so2, so2, ub);

    // D3: out-only u3 -> uC, i3 -> ieB(iC); folded in finalize
    SpmmOp u3{rPu, ent_sorted, iB, uC, nullptr, nullptr, 0.f, 0.f, NUM_USERS};
    SpmmOp i3{rPi, ent_sorted, uB, iCb, nullptr, nullptr, 0.f, 0.f, NUM_ITEMS};
    spmm2<<<ub + ib, blk, 0, stream>>>(u3, i3, ub);

    finalize_kernel<<<(NUM_USERS + NUM_ITEMS + 3) / 4, blk, 0, stream>>>(
        (float*)d_out, uC, s2b, iCb);
}

// Round 18
// 630.521 us; speedup vs baseline: 1.0716x; 1.0716x over previous
//
#include <hip/hip_runtime.h>

constexpr int NUM_USERS = 100000;
constexpr int NUM_ITEMS = 50000;
constexpr int DIM = 64;
constexpr int NNZ_R = 3200000;
constexpr int NNZ_S = 2000000;
constexpr int NNZ_TOT = NNZ_R + NNZ_R + NNZ_S;   // 8.4M entries, one array

constexpr int BSH_U = 8, BROWS_U = 256;     // user/social buckets: 256 rows
constexpr int BSH_I = 7, BROWS_I = 128;     // item buckets: 128 rows
constexpr int NC_U = (NUM_USERS + BROWS_U - 1) / BROWS_U;   // 391
constexpr int NC_I = (NUM_ITEMS + BROWS_I - 1) / BROWS_I;   // 391
constexpr int NC_S = NC_U;                                  // 391
constexpr int NC = NC_U + NC_I + NC_S;                      // 1173
constexpr int NBLK = 256;                   // build blocks, 1/CU
constexpr int NPB = NBLK * NC;
constexpr int CHUNK_R = NNZ_R / NBLK;       // 12500 exact
constexpr int CHUNK_S = (NNZ_S + NBLK - 1) / NBLK;  // 7813

constexpr int SB_EDGES = 4096;              // R sub-batch: 4096 edges -> 8192 entries
constexpr int SB_PAIRS = 8192;

__device__ __forceinline__ float bf2f(unsigned short u) {
    return __uint_as_float((unsigned)u << 16);
}
__device__ __forceinline__ unsigned short f2bf(float f) {   // round-to-nearest-even
    unsigned u = __float_as_uint(f);
    return (unsigned short)((u + 0x7FFFu + ((u >> 16) & 1u)) >> 16);
}
__device__ __forceinline__ float bflo(unsigned r) { return __uint_as_float(r << 16); }
__device__ __forceinline__ float bfhi(unsigned r) { return __uint_as_float(r & 0xFFFF0000u); }

// ---- pass A: LDS histogram; per-(block,bucket) counts BUCKET-MAJOR ----
__global__ __launch_bounds__(1024) void hist_lds(const int* __restrict__ rr,
                                                 const int* __restrict__ rc,
                                                 const int* __restrict__ sr,
                                                 int* __restrict__ cntPB /* [NC][NBLK] */) {
    __shared__ int lds[NC];
    int k = blockIdx.x, tid = threadIdx.x;
    for (int c = tid; c < NC; c += 1024) lds[c] = 0;
    __syncthreads();
    int r0 = k * CHUNK_R, r1 = r0 + CHUNK_R;
    int s0 = k * CHUNK_S, s1 = min(s0 + CHUNK_S, NNZ_S);
    for (int i = r0 + tid; i < r1; i += 1024) {
        atomicAdd(&lds[rr[i] >> BSH_U], 1);
        atomicAdd(&lds[NC_U + (rc[i] >> BSH_I)], 1);
    }
    for (int i = s0 + tid; i < s1; i += 1024)
        atomicAdd(&lds[NC_U + NC_I + (sr[i] >> BSH_U)], 1);
    __syncthreads();
    for (int c = tid; c < NC; c += 1024) cntPB[c * NBLK + k] = lds[c];
}

// ---- per-bucket exscan over NBLK block-counts (one block per bucket) ----
__global__ __launch_bounds__(NBLK) void scan_bkt(int* __restrict__ cntPB,
                                                 int* __restrict__ bktTot) {
    int c = blockIdx.x, t = threadIdx.x;
    __shared__ int sh[NBLK];
    int v = cntPB[c * NBLK + t];
    sh[t] = v;
    __syncthreads();
    for (int off = 1; off < NBLK; off <<= 1) {
        int u = (t >= off) ? sh[t - off] : 0;
        __syncthreads();
        sh[t] += u;
        __syncthreads();
    }
    cntPB[c * NBLK + t] = sh[t] - v;
    if (t == NBLK - 1) bktTot[c] = sh[t];
}

// ---- tiny top-level exscan over NC bucket totals ----
__global__ __launch_bounds__(1024) void scan_top(int* __restrict__ B /* NC+1 */) {
    __shared__ int part[1024];
    int t = threadIdx.x;
    const int chunk = (NC + 1023) >> 10;
    int lo = t * chunk, hi = min(lo + chunk, NC);
    int s = 0;
    for (int i = lo; i < hi; ++i) s += B[i];
    part[t] = s;
    __syncthreads();
    for (int off = 1; off < 1024; off <<= 1) {
        int v = (t >= off) ? part[t - off] : 0;
        __syncthreads();
        part[t] += v;
        __syncthreads();
    }
    int excl = (t == 0) ? 0 : part[t - 1];
    for (int i = lo; i < hi; ++i) {
        int v = B[i];
        B[i] = excl;
        excl += v;
    }
    if (t == 1023) B[NC] = part[1023];
}

// ---- pass B: LDS-staged sub-batch sort, then wave-coalesced contiguous writes ----
__global__ __launch_bounds__(1024) void bin_pass(const int* __restrict__ rr,
                                                 const int* __restrict__ rc,
                                                 const float* __restrict__ rv,
                                                 const int* __restrict__ sr,
                                                 const int* __restrict__ sc,
                                                 const float* __restrict__ sv,
                                                 const int* __restrict__ cntPB,
                                                 const int* __restrict__ bktBase,
                                                 int2* __restrict__ ent) {
    __shared__ int cur[NC];
    __shared__ int cnt[NC];
    __shared__ int lstart[NC];
    __shared__ int lcur[NC];
    __shared__ int part[1024];
    __shared__ int2 stage[SB_PAIRS];
    __shared__ int gaddr[SB_PAIRS];
    int k = blockIdx.x, tid = threadIdx.x;
    for (int c = tid; c < NC; c += 1024)
        cur[c] = bktBase[c] + cntPB[c * NBLK + k];

    int r0 = k * CHUNK_R;
    for (int sb = 0; sb < CHUNK_R; sb += SB_EDGES) {
        int nE = min(SB_EDGES, CHUNK_R - sb);
        int base = r0 + sb;
        for (int c = tid; c < NC; c += 1024) { cnt[c] = 0; lcur[c] = 0; }
        __syncthreads();
        for (int i = tid; i < nE; i += 1024) {
            atomicAdd(&cnt[rr[base + i] >> BSH_U], 1);
            atomicAdd(&cnt[NC_U + (rc[base + i] >> BSH_I)], 1);
        }
        __syncthreads();
        int o0 = 2 * tid, o1 = 2 * tid + 1;
        int a = (o0 < NC) ? cnt[o0] : 0;
        int b = (o1 < NC) ? cnt[o1] : 0;
        part[tid] = a + b;
        __syncthreads();
        for (int off = 1; off < 1024; off <<= 1) {
            int v = (tid >= off) ? part[tid - off] : 0;
            __syncthreads();
            part[tid] += v;
            __syncthreads();
        }
        int ex = (tid == 0) ? 0 : part[tid - 1];
        if (o0 < NC) lstart[o0] = ex;
        if (o1 < NC) lstart[o1] = ex + a;
        __syncthreads();
        for (int i = tid; i < nE; i += 1024) {
            int r = rr[base + i], c = rc[base + i];
            int v = __float_as_int(rv[base + i]);
            int cu_ = r >> BSH_U;
            int j = atomicAdd(&lcur[cu_], 1);
            int lp = lstart[cu_] + j;
            stage[lp] = make_int2(((r & (BROWS_U - 1)) << 17) | c, v);
            gaddr[lp] = cur[cu_] + j;
            int ci_ = NC_U + (c >> BSH_I);
            int j2 = atomicAdd(&lcur[ci_], 1);
            int lp2 = lstart[ci_] + j2;
            stage[lp2] = make_int2(((c & (BROWS_I - 1)) << 17) | r, v);
            gaddr[lp2] = cur[ci_] + j2;
        }
        __syncthreads();
        int nP = 2 * nE;
        for (int s = tid; s < nP; s += 1024)
            ent[gaddr[s]] = stage[s];
        for (int c = tid; c < NC; c += 1024) cur[c] += cnt[c];
        __syncthreads();
    }

    int s0 = k * CHUNK_S, sEnd = min(s0 + CHUNK_S, NNZ_S);
    for (int sb = s0; sb < sEnd; sb += SB_PAIRS) {
        int nE = min(SB_PAIRS, sEnd - sb);
        for (int c = tid; c < NC; c += 1024) { cnt[c] = 0; lcur[c] = 0; }
        __syncthreads();
        for (int i = tid; i < nE; i += 1024)
            atomicAdd(&cnt[NC_U + NC_I + (sr[sb + i] >> BSH_U)], 1);
        __syncthreads();
        int o0 = 2 * tid, o1 = 2 * tid + 1;
        int a = (o0 < NC) ? cnt[o0] : 0;
        int b = (o1 < NC) ? cnt[o1] : 0;
        part[tid] = a + b;
        __syncthreads();
        for (int off = 1; off < 1024; off <<= 1) {
            int v = (tid >= off) ? part[tid - off] : 0;
            __syncthreads();
            part[tid] += v;
            __syncthreads();
        }
        int ex = (tid == 0) ? 0 : part[tid - 1];
        if (o0 < NC) lstart[o0] = ex;
        if (o1 < NC) lstart[o1] = ex + a;
        __syncthreads();
        for (int i = tid; i < nE; i += 1024) {
            int r = sr[sb + i];
            int cs_ = NC_U + NC_I + (r >> BSH_U);
            int j = atomicAdd(&lcur[cs_], 1);
            int lp = lstart[cs_] + j;
            stage[lp] = make_int2(((r & (BROWS_U - 1)) << 17) | sc[sb + i],
                                  __float_as_int(sv[sb + i]));
            gaddr[lp] = cur[cs_] + j;
        }
        __syncthreads();
        for (int s = tid; s < nE; s += 1024)
            ent[gaddr[s]] = stage[s];
        for (int c = tid; c < NC; c += 1024) cur[c] += cnt[c];
        __syncthreads();
    }
}

// ---- per-bucket counting sort (<=256 local rows) ----
__global__ __launch_bounds__(512) void sort_buckets(const int2* __restrict__ src,
                                                    int2* __restrict__ dst,
                                                    const int* __restrict__ bktBase,
                                                    int* __restrict__ rPu,
                                                    int* __restrict__ rPi,
                                                    int* __restrict__ rPs) {
    int gb = blockIdx.x;
    int* rowptr;
    int brows, lb, nrows;
    if (gb < NC_U)              { rowptr = rPu; brows = BROWS_U; lb = gb;               nrows = NUM_USERS; }
    else if (gb < NC_U + NC_I)  { rowptr = rPi; brows = BROWS_I; lb = gb - NC_U;        nrows = NUM_ITEMS; }
    else                        { rowptr = rPs; brows = BROWS_U; lb = gb - NC_U - NC_I; nrows = NUM_USERS; }
    int t = threadIdx.x;
    __shared__ int cnt[256];
    __shared__ int part[256];
    __shared__ int ofs[256];
    if (t < 256) cnt[t] = 0;
    __syncthreads();
    int b0 = bktBase[gb], b1 = bktBase[gb + 1];
    for (int i = b0 + t; i < b1; i += 512)
        atomicAdd(&cnt[(unsigned)src[i].x >> 17], 1);
    __syncthreads();
    if (t < 256) part[t] = cnt[t];
    __syncthreads();
    for (int off = 1; off < 256; off <<= 1) {
        int v = 0;
        if (t < 256 && t >= off) v = part[t - off];
        __syncthreads();
        if (t < 256) part[t] += v;
        __syncthreads();
    }
    if (t < 256) ofs[t] = part[t] - cnt[t];
    __syncthreads();
    int gr = lb * brows + t;
    if (t < brows && gr < nrows) rowptr[gr] = b0 + ofs[t];
    if (gb == 0 && t == 0) {
        rPu[NUM_USERS] = NNZ_R;
        rPi[NUM_ITEMS] = 2 * NNZ_R;
        rPs[NUM_USERS] = NNZ_TOT;
    }
    __syncthreads();
    for (int i = b0 + t; i < b1; i += 512) {
        int2 v = src[i];
        int lr = (unsigned)v.x >> 17;
        int pos = b0 + atomicAdd(&ofs[lr], 1);
        dst[pos] = make_int2(v.x & 0x1FFFF, v.y);
    }
}

// ---- CSR SpMM with acc-traffic elimination:
//      initsrc != null : acc = w0*bf16(initsrc) + w*sum   (no acc read)
//      initsrc == null, acc != null : acc += w*sum        (RMW)
//      acc == null : bf16 out only                        (deferred to finalize) ----
struct SpmmOp {
    const int* rowptr;
    const int2* ent;
    const unsigned short* x;        // bf16 rows [*][64]
    unsigned short* out;            // bf16, nullable
    float* acc;                     // f32 (d_out), nullable
    const unsigned short* initsrc;  // bf16 init term, nullable
    float w;
    float w0;
    int nrows;
};

__global__ __launch_bounds__(256, 4) void spmm2(SpmmOp A, SpmmOp B, int ablocks) {
    bool isA = (int)blockIdx.x < ablocks;
    SpmmOp op = isA ? A : B;
    int bid = isA ? blockIdx.x : blockIdx.x - ablocks;
    int row = bid * 4 + (threadIdx.x >> 6);
    if (row >= op.nrows) return;
    int lane = threadIdx.x & 63;
    int g = lane >> 4;          // edge group 0..3
    int q = lane & 15;          // quarter-row slot: dims 4q..4q+3
    const int2* __restrict__ ent = op.ent;
    const unsigned short* __restrict__ x = op.x;
    int e = op.rowptr[row], end = op.rowptr[row + 1];
    float s0 = 0.f, s1 = 0.f, s2 = 0.f, s3 = 0.f;
    for (; e + 16 <= end; e += 16) {            // 4 edges per group, 16 per wave-iter
        int2 n0 = ent[e + g];
        int2 n1 = ent[e + 4 + g];
        int2 n2 = ent[e + 8 + g];
        int2 n3 = ent[e + 12 + g];
        uint2 r0 = *reinterpret_cast<const uint2*>(x + (size_t)n0.x * DIM + q * 4);
        uint2 r1 = *reinterpret_cast<const uint2*>(x + (size_t)n1.x * DIM + q * 4);
        uint2 r2 = *reinterpret_cast<const uint2*>(x + (size_t)n2.x * DIM + q * 4);
        uint2 r3 = *reinterpret_cast<const uint2*>(x + (size_t)n3.x * DIM + q * 4);
        float v0 = __int_as_float(n0.y), v1 = __int_as_float(n1.y);
        float v2 = __int_as_float(n2.y), v3 = __int_as_float(n3.y);
        s0 += v0 * bflo(r0.x); s1 += v0 * bfhi(r0.x); s2 += v0 * bflo(r0.y); s3 += v0 * bfhi(r0.y);
        s0 += v1 * bflo(r1.x); s1 += v1 * bfhi(r1.x); s2 += v1 * bflo(r1.y); s3 += v1 * bfhi(r1.y);
        s0 += v2 * bflo(r2.x); s1 += v2 * bfhi(r2.x); s2 += v2 * bflo(r2.y); s3 += v2 * bfhi(r2.y);
        s0 += v3 * bflo(r3.x); s1 += v3 * bfhi(r3.x); s2 += v3 * bflo(r3.y); s3 += v3 * bfhi(r3.y);
    }
    if (e < end) {                              // single predicated 16-wide tail step
        int t0 = e + 4 * g;
        int lim = end - 1;
        int c0 = min(t0, lim),     c1 = min(t0 + 1, lim);
        int c2 = min(t0 + 2, lim), c3 = min(t0 + 3, lim);
        int2 n0 = ent[c0];
        int2 n1 = ent[c1];
        int2 n2 = ent[c2];
        int2 n3 = ent[c3];
        uint2 r0 = *reinterpret_cast<const uint2*>(x + (size_t)n0.x * DIM + q * 4);
        uint2 r1 = *reinterpret_cast<const uint2*>(x + (size_t)n1.x * DIM + q * 4);
        uint2 r2 = *reinterpret_cast<const uint2*>(x + (size_t)n2.x * DIM + q * 4);
        uint2 r3 = *reinterpret_cast<const uint2*>(x + (size_t)n3.x * DIM + q * 4);
        float v0 = (t0     < end) ? __int_as_float(n0.y) : 0.f;
        float v1 = (t0 + 1 < end) ? __int_as_float(n1.y) : 0.f;
        float v2 = (t0 + 2 < end) ? __int_as_float(n2.y) : 0.f;
        float v3 = (t0 + 3 < end) ? __int_as_float(n3.y) : 0.f;
        s0 += v0 * bflo(r0.x); s1 += v0 * bfhi(r0.x); s2 += v0 * bflo(r0.y); s3 += v0 * bfhi(r0.y);
        s0 += v1 * bflo(r1.x); s1 += v1 * bfhi(r1.x); s2 += v1 * bflo(r1.y); s3 += v1 * bfhi(r1.y);
        s0 += v2 * bflo(r2.x); s1 += v2 * bfhi(r2.x); s2 += v2 * bflo(r2.y); s3 += v2 * bfhi(r2.y);
        s0 += v3 * bflo(r3.x); s1 += v3 * bfhi(r3.x); s2 += v3 * bflo(r3.y); s3 += v3 * bfhi(r3.y);
    }
    s0 += __shfl_xor(s0, 16, 64); s0 += __shfl_xor(s0, 32, 64);
    s1 += __shfl_xor(s1, 16, 64); s1 += __shfl_xor(s1, 32, 64);
    s2 += __shfl_xor(s2, 16, 64); s2 += __shfl_xor(s2, 32, 64);
    s3 += __shfl_xor(s3, 16, 64); s3 += __shfl_xor(s3, 32, 64);
    if (g == 0) {                               // 16 lanes write the full row
        size_t base = (size_t)row * DIM + q * 4;
        if (op.out) {
            uint2 o;
            o.x = (unsigned)f2bf(s0) | ((unsigned)f2bf(s1) << 16);
            o.y = (unsigned)f2bf(s2) | ((unsigned)f2bf(s3) << 16);
            *reinterpret_cast<uint2*>(op.out + base) = o;
        }
        if (op.acc) {
            float4* a = reinterpret_cast<float4*>(op.acc + base);
            float4 av;
            if (op.initsrc) {
                uint2 iv = *reinterpret_cast<const uint2*>(op.initsrc + base);
                av.x = op.w0 * bflo(iv.x); av.y = op.w0 * bfhi(iv.x);
                av.z = op.w0 * bflo(iv.y); av.w = op.w0 * bfhi(iv.y);
            } else {
                av = *a;
            }
            av.x += op.w * s0; av.y += op.w * s1; av.z += op.w * s2; av.w += op.w * s3;
            *a = av;
        }
    }
}

// bf16 copies of the input embeddings (runs after build; aliases ent_bin region)
__global__ void to_bf16(const float* __restrict__ ue, const float* __restrict__ ie,
                        unsigned short* __restrict__ ueB, unsigned short* __restrict__ ieB,
                        int u4, int i4) {
    int i = blockIdx.x * blockDim.x + threadIdx.x;
    int st = gridDim.x * blockDim.x;
    int n4 = u4 + i4;
    for (; i < n4; i += st) {
        if (i < u4) {
            float4 v = reinterpret_cast<const float4*>(ue)[i];
            ushort4 b;
            b.x = f2bf(v.x); b.y = f2bf(v.y); b.z = f2bf(v.z); b.w = f2bf(v.w);
            reinterpret_cast<ushort4*>(ueB)[i] = b;
        } else {
            int j = i - u4;
            float4 v = reinterpret_cast<const float4*>(ie)[j];
            ushort4 b;
            b.x = f2bf(v.x); b.y = f2bf(v.y); b.z = f2bf(v.z); b.w = f2bf(v.w);
            reinterpret_cast<ushort4*>(ieB)[j] = b;
        }
    }
}

// finalize: fold deferred last-layer terms, then L2-normalize per row
__global__ void finalize_kernel(float* __restrict__ out,
                                const unsigned short* __restrict__ uC,  // u3
                                const unsigned short* __restrict__ s2,  // social layer 2
                                const unsigned short* __restrict__ iC) { // i3
    const float WU = 0.6f / 4.0f, WS = 0.4f / 3.0f, WI = 0.25f;
    int row = blockIdx.x * 4 + (threadIdx.x >> 6);
    if (row >= NUM_USERS + NUM_ITEMS) return;
    int d = threadIdx.x & 63;
    size_t idx = (size_t)row * DIM + d;
    float val = out[idx];
    if (row < NUM_USERS) {
        val += WU * bf2f(uC[idx]) + WS * bf2f(s2[idx]);
    } else {
        size_t iidx = idx - (size_t)NUM_USERS * DIM;
        val += WI * bf2f(iC[iidx]);
    }
    float sq = val * val;
    #pragma unroll
    for (int off = 32; off; off >>= 1) sq += __shfl_xor(sq, off, 64);
    out[idx] = val / fmaxf(sqrtf(sq), 1e-12f);
}

extern "C" void kernel_launch(void* const* d_in, const int* in_sizes, int n_in,
                              void* d_out, int out_size, void* d_ws, size_t ws_size,
                              hipStream_t stream) {
    const float* user_emb = (const float*)d_in[0];
    const float* item_emb = (const float*)d_in[1];
    const float* r_vals   = (const float*)d_in[2];
    const float* s_vals   = (const float*)d_in[3];
    const int*   r_rows   = (const int*)d_in[4];
    const int*   r_cols   = (const int*)d_in[5];
    const int*   s_rows   = (const int*)d_in[6];
    const int*   s_cols   = (const int*)d_in[7];

    const size_t U = (size_t)NUM_USERS * DIM;
    const size_t I = (size_t)NUM_ITEMS * DIM;

    // ---- workspace (~140 MB) ----
    int2* ent_sorted = (int2*)d_ws;                       // NNZ_TOT (67.2 MB), persistent
    char* region2 = (char*)(ent_sorted + NNZ_TOT);        // 70.4 MB union:
    int2* ent_bin = (int2*)region2;                       //   build-time entries (67.2)
    unsigned short* ueB = (unsigned short*)region2;       //   bf16: [ueB U][ieB I][uA U]
    unsigned short* ieB = ueB + U;                        //         [uB U][iA I][iB I][uC U]
    unsigned short* uA  = ieB + I;                        //   = (4U+3I)*2 = 70.4 MB
    unsigned short* uB  = uA + U;
    unsigned short* iA  = uB + U;
    unsigned short* iB  = iA + I;
    unsigned short* uC  = iB + I;
    unsigned short* s1b = uA;    // social 1 out: uA dead after D2
    unsigned short* s2b = ueB;   // social 2 out: ueB dead after so1
    unsigned short* iCb = ieB;   // i3 out: ieB dead after D1
    int* cntPB   = (int*)(uC + U);                        // [NC][NBLK] (1.2 MB)
    int* bktBase = cntPB + NPB;                           // NC+1
    int* rPu = bktBase + NC + 1;                          // NUM_USERS+1
    int* rPi = rPu + NUM_USERS + 1;                       // NUM_ITEMS+1
    int* rPs = rPi + NUM_ITEMS + 1;                       // NUM_USERS+1

    float* accU = (float*)d_out;
    float* accI = (float*)d_out + U;

    dim3 blk(256);

    // ---- build: hist -> per-bucket scan -> top scan -> staged scatter -> sort ----
    hist_lds<<<NBLK, 1024, 0, stream>>>(r_rows, r_cols, s_rows, cntPB);
    scan_bkt<<<NC, NBLK, 0, stream>>>(cntPB, bktBase);
    scan_top<<<1, 1024, 0, stream>>>(bktBase);
    bin_pass<<<NBLK, 1024, 0, stream>>>(r_rows, r_cols, r_vals, s_rows, s_cols, s_vals,
                                        cntPB, bktBase, ent_bin);
    sort_buckets<<<NC, 512, 0, stream>>>(ent_bin, ent_sorted, bktBase, rPu, rPi, rPs);

    to_bf16<<<2048, blk, 0, stream>>>(user_emb, item_emb, ueB, ieB,
                                      (int)(U / 4), (int)(I / 4));

    const float WU = 0.6f / 4.0f, WI = 0.25f, WS = 0.4f / 3.0f;
    const float WU0 = WU + WS;   // e_u weight: 0.15 + 0.4/3
    int ub = (NUM_USERS + 3) / 4, ib = (NUM_ITEMS + 3) / 4;

    // D1: acc-init (no acc read): accU = WU0*e_u + WU*u1 ; accI = WI*e_i + WI*i1
    SpmmOp u1{rPu, ent_sorted, ieB, uA, accU, ueB, WU, WU0, NUM_USERS};
    SpmmOp i1{rPi, ent_sorted, ueB, iA, accI, ieB, WI, WI, NUM_ITEMS};
    spmm2<<<ub + ib, blk, 0, stream>>>(u1, i1, ub);

    // D2: RMW
    SpmmOp u2{rPu, ent_sorted, iA, uB, accU, nullptr, WU, 0.f, NUM_USERS};
    SpmmOp i2{rPi, ent_sorted, uA, iB, accI, nullptr, WI, 0.f, NUM_ITEMS};
    spmm2<<<ub + ib, blk, 0, stream>>>(u2, i2, ub);

    // so1: RMW accU += WS*s1, out s1 (into uA, dead after D2)
    SpmmOp so1{rPs, ent_sorted, ueB, s1b, accU, nullptr, WS, 0.f, NUM_USERS};
    spmm2<<<ub, blk, 0, stream>>>(so1, so1, ub);

    // so2: out-only s2 (into ueB, dead after so1); folded in finalize
    SpmmOp so2{rPs, ent_sorted, s1b, s2b, nullptr, nullptr, 0.f, 0.f, NUM_USERS};
    spmm2<<<ub, blk, 0, stream>>>(so2, so2, ub);

    // D3: out-only u3 -> uC, i3 -> ieB(iC); folded in finalize
    SpmmOp u3{rPu, ent_sorted, iB, uC, nullptr, nullptr, 0.f, 0.f, NUM_USERS};
    SpmmOp i3{rPi, ent_sorted, uB, iCb, nullptr, nullptr, 0.f, 0.f, NUM_ITEMS};
    spmm2<<<ub + ib, blk, 0, stream>>>(u3, i3, ub);

    finalize_kernel<<<(NUM_USERS + NUM_ITEMS + 3) / 4, blk, 0, stream>>>(
        (float*)d_out, uC, s2b, iCb);
}